// Round 15
// baseline (546.145 us; speedup 1.0000x reference)
//
#include <hip/hip_runtime.h>

#define NLOC  10
#define NGI   13
#define NPAIR 55
#define EPB   16           // elements per block
#define TPB   64           // 1 wave; 4 threads per element
// NOTE: assumes nele % 4 == 0 for dw granule tiling (here nele = 500000, rem always 16)

// LDS floats: [nx-half 16*132=2112][dw 208][n 130] = 2450 fl = 9800 B
// -> 16 blocks/CU, 4 waves/SIMD: first config above 2 waves/SIMD.
#define W_DW   2112
#define W_N    2320
#define W_TOT  2450

typedef float vf2 __attribute__((ext_vector_type(2)));

__device__ __forceinline__ constexpr int pidx(int i, int j) {   // requires i<=j
    return i * NLOC - (i * (i - 1)) / 2 + (j - i);
}

// async global->LDS, 16B/lane; lds base wave-uniform, HW adds lane*16
__device__ __forceinline__ void stage16(const float* gsrc, float* lds) {
    __builtin_amdgcn_global_load_lds(
        (const __attribute__((address_space(1))) void*)gsrc,
        (__attribute__((address_space(3))) void*)lds, 16, 0, 0);
}

__global__ __launch_bounds__(TPB, 4) void fem_kernel(
    const float* __restrict__ r0g,
    const float* __restrict__ cig,
    const float* __restrict__ cng,
    const float* __restrict__ kp,
    const float* __restrict__ dtp,
    const float* __restrict__ nmat,
    const float* __restrict__ nx,
    const float* __restrict__ dwei,
    float* __restrict__ out,
    int nele)
{
    __shared__ float sm[W_TOT];

    const int  t   = threadIdx.x;
    const long e0  = (long)blockIdx.x * EPB;
    const int  rem = min(EPB, nele - (int)e0);

    const int  eloc = t >> 2;
    const int  q    = t & 3;             // g-slot: g = q + 4*it
    const long e    = e0 + eloc;
    const bool live = eloc < rem;
    const long ee   = live ? e : (long)(nele - 1);

    const float kk  = kp[0];
    const float idt = 1.0f / dtp[0];

    // early: n table + ci/cn (latency hides under stage-A drain)
    for (int w = t; w < 130; w += TPB) sm[W_N + w] = nmat[w];

    float civ[NLOC], dif[NLOC];
    {
        const vf2* ci2 = reinterpret_cast<const vf2*>(cig + (size_t)ee * 10);
        const vf2* cn2 = reinterpret_cast<const vf2*>(cng + (size_t)ee * 10);
        #pragma unroll
        for (int u2 = 0; u2 < 5; ++u2) {
            vf2 a = ci2[u2], b = cn2[u2];
            civ[2*u2]   = a.x; civ[2*u2+1] = a.y;
            dif[2*u2]   = b.x - a.x; dif[2*u2+1] = b.y - a.y;
        }
    }

    // ---- stage A: dim0 halves (33 aligned granules/elem, elem base 1040B) + dw
    #pragma unroll
    for (int k2 = 0; k2 < 10; ++k2) {
        const int G = k2 * TPB + t;                 // LDS float idx = 4*G
        if (G < 528) {
            const int u = G / 33, r = G - u * 33;   // r=32 reads 2 junk floats (in-bounds)
            if (e0 + u < nele)
                stage16(nx + ((size_t)(e0 + u) * 260 + r * 4), sm + k2 * 256);
        } else if (G < 580) {
            const int rel = (G - 528) * 4;          // rem*13 is granule-exact for rem=16
            if (rel + 4 <= rem * 13)
                stage16(dwei + (size_t)e0 * 13 + rel, sm + k2 * 256);
        }
    }
    asm volatile("s_waitcnt vmcnt(0)" ::: "memory");

    const float* smn  = sm + W_N;
    const float* smdw = sm + W_DW + eloc * 13;
    const float* smx0 = sm + eloc * 132;            // [f0..f129, junk, junk]

    float acc[NPAIR];
    #pragma unroll
    for (int p = 0; p < NPAIR; ++p) acc[p] = 0.0f;
    float r0a[NLOC];
    #pragma unroll
    for (int i = 0; i < NLOC; ++i) r0a[i] = 0.0f;

    // ---- phase A compute: stiffness dim0 (g = q+4it) ----
    #pragma unroll
    for (int it = 0; it < 4; ++it) {
        const int   graw = q + 4 * it;
        const int   g    = graw < NGI ? graw : NGI - 1;
        const float wv   = graw < NGI ? kk * smdw[g] : 0.0f;
        float col[NLOC];
        #pragma unroll
        for (int l = 0; l < NLOC; ++l) col[l] = smx0[l * 13 + g];
        float u = 0.0f;
        #pragma unroll
        for (int l = 0; l < NLOC; ++l) u = fmaf(col[l], civ[l], u);
        const float uw = u * wv;
        #pragma unroll
        for (int i = 0; i < NLOC; ++i) {
            const float ti = col[i] * wv;
            #pragma unroll
            for (int j = i; j < NLOC; ++j)
                acc[pidx(i, j)] = fmaf(ti, col[j], acc[pidx(i, j)]);
            r0a[i] = fmaf(-col[i], uw, r0a[i]);
        }
    }
    // ---- mass (needs only n + dw): same g-split ----
    #pragma unroll
    for (int it = 0; it < 4; ++it) {
        const int   graw = q + 4 * it;
        const int   g    = graw < NGI ? graw : NGI - 1;
        const float wv   = graw < NGI ? idt * smdw[g] : 0.0f;
        float ncol[NLOC];
        #pragma unroll
        for (int l = 0; l < NLOC; ++l) ncol[l] = smn[l * 13 + g];
        float wd = 0.0f;
        #pragma unroll
        for (int l = 0; l < NLOC; ++l) wd = fmaf(ncol[l], dif[l], wd);
        #pragma unroll
        for (int i = 0; i < NLOC; ++i) {
            const float ti = ncol[i] * wv;
            #pragma unroll
            for (int j = i; j < NLOC; ++j)
                acc[pidx(i, j)] = fmaf(ti, ncol[j], acc[pidx(i, j)]);
            r0a[i] = fmaf(ti, wd, r0a[i]);
        }
    }

    // all dim0 ds_reads must complete before DMA overwrites the buffer
    asm volatile("s_waitcnt lgkmcnt(0)" ::: "memory");
    __builtin_amdgcn_sched_barrier(0);

    // ---- stage B: dim1 halves, aligned via 8B-early base (elem*1040+512) ----
    #pragma unroll
    for (int k2 = 0; k2 < 9; ++k2) {
        const int G = k2 * TPB + t;
        if (G < 528) {
            const int u = G / 33, r = G - u * 33;   // r=0 carries 2 junk floats
            if (e0 + u < nele)
                stage16(nx + ((size_t)(e0 + u) * 260 + 128 + r * 4), sm + k2 * 256);
        }
    }
    asm volatile("s_waitcnt vmcnt(0)" ::: "memory");

    const float* smx1 = sm + eloc * 132 + 2;        // valid dim1 starts at +2

    // ---- phase B compute: stiffness dim1 ----
    #pragma unroll
    for (int it = 0; it < 4; ++it) {
        const int   graw = q + 4 * it;
        const int   g    = graw < NGI ? graw : NGI - 1;
        const float wv   = graw < NGI ? kk * smdw[g] : 0.0f;
        float col[NLOC];
        #pragma unroll
        for (int l = 0; l < NLOC; ++l) col[l] = smx1[l * 13 + g];
        float u = 0.0f;
        #pragma unroll
        for (int l = 0; l < NLOC; ++l) u = fmaf(col[l], civ[l], u);
        const float uw = u * wv;
        #pragma unroll
        for (int i = 0; i < NLOC; ++i) {
            const float ti = col[i] * wv;
            #pragma unroll
            for (int j = i; j < NLOC; ++j)
                acc[pidx(i, j)] = fmaf(ti, col[j], acc[pidx(i, j)]);
            r0a[i] = fmaf(-col[i], uw, r0a[i]);
        }
    }

    // combine the 4 partial sums (quad butterfly)
    #pragma unroll
    for (int p = 0; p < NPAIR; ++p) {
        acc[p] += __shfl_xor(acc[p], 1);
        acc[p] += __shfl_xor(acc[p], 2);
    }
    #pragma unroll
    for (int i = 0; i < NLOC; ++i) {
        r0a[i] += __shfl_xor(r0a[i], 1);
        r0a[i] += __shfl_xor(r0a[i], 2);
    }

    // ---- epilogue: rows split by (i&3)==q, literal indices ----
    if (live) {
        float* obd = out + (size_t)e * 100;
        float* odg = out + (size_t)nele * 100 + (size_t)e * 10;
        float* oro = out + (size_t)nele * 110 + (size_t)e * 10;
        const float* r0s = r0g + (size_t)e * 10;
        #pragma unroll
        for (int i = 0; i < NLOC; ++i) {
            if ((i & 3) == q) {
                float row[NLOC];
                #pragma unroll
                for (int j = 0; j < NLOC; ++j) {
                    const int lo = i < j ? i : j, hi = i < j ? j : i;
                    row[j] = acc[pidx(lo, hi)];
                }
                #pragma unroll
                for (int u2 = 0; u2 < 5; ++u2) {
                    vf2 v = { row[2*u2], row[2*u2+1] };
                    *reinterpret_cast<vf2*>(obd + i * 10 + 2 * u2) = v;
                }
                odg[i] = row[i];
                oro[i] = r0s[i] + r0a[i];
            }
        }
    }
}

extern "C" void kernel_launch(void* const* d_in, const int* in_sizes, int n_in,
                              void* d_out, int out_size, void* d_ws, size_t ws_size,
                              hipStream_t stream) {
    const float* r0   = (const float*)d_in[0];
    const float* ci   = (const float*)d_in[1];
    const float* cn   = (const float*)d_in[2];
    const float* k    = (const float*)d_in[3];
    const float* dt   = (const float*)d_in[4];
    const float* nmat = (const float*)d_in[5];
    const float* nx   = (const float*)d_in[6];
    const float* dw   = (const float*)d_in[7];
    const int nele = in_sizes[7] / NGI;

    const int nb = (nele + EPB - 1) / EPB;
    fem_kernel<<<nb, TPB, 0, stream>>>(r0, ci, cn, k, dt, nmat, nx, dw,
                                       (float*)d_out, nele);
}